// Round 9
// baseline (76981.287 us; speedup 1.0000x reference)
//
#include <hip/hip_runtime.h>
#include <math.h>

// LSTM T=32768, B=1, I=128, H=512. Persistent kernel: 32 WGs x 512 threads.
// R20 = R12 (best verified 65.5ms: single MALL rail, __syncthreads barriers,
// coalesced publish, tag-in-band packets) + PIPELINED COUNTED-VMCNT POLL:
//   * Evidence: transport swaps (L2 rail) and barrier swaps (lgkm) are both
//     A/B-falsified as the floor (R15-R19). The untouched term is wave0's
//     serial poll: 4 loads + vmcnt(0) per iter = detect granularity ~1 MALL
//     RTT, plus wave0's own publish stores drained by the first poll iter.
//   * Fix 1: two 4-load batches in flight, s_waitcnt vmcnt(4) waits only the
//     OLDER batch (oldest-first, m135) -> ~2 checks per RTT. Leftover loads
//     at break are oldest next step and drain for free inside vmcnt(4).
//   * Fix 2: publisher = rotating compute wave (2 + t%6) (placement verified
//     harmless R16-R19) so wave0's vmem = poll loads ONLY -> counted waits
//     exact, no publish self-drain.
//   * Safety ladder: 48 failed checks -> per-step fallback to the R12-proven
//     __hip_atomic_load loop; >=8 fallback steps -> sticky atomic mode
//     (~R12 perf). Wrong cache-flag guesses can only cost speed, never
//     correctness.
//   * Wire: 8-bit in-band tag ((t&15) in h_even low nibble, ((t>>4)&15) in
//     h_odd low nibble) + t=0 zero-synthesis (R15+-verified).
// Compute datapath, barriers, x prefetch: byte-identical to R12.

#define T_SEQ 32768
#define HID   512
#define INP   128
#define NWG   32    // workgroups (grid)
#define NTH   512   // 8 waves; wave0 polls then computes
#define HSL   16    // h elements per WG
#define KW    64    // W_hh weights per thread
#define KX    16    // W_ih weights per thread
#define NPK   256   // packets per parity (2 h each)
#define FT    48    // pipelined-poll checks before per-step fallback

typedef unsigned long long u64;
typedef unsigned int u32;

__device__ __forceinline__ float fast_sigmoid(float x) {
    return 1.0f / (1.0f + __expf(-x));
}
__device__ __forceinline__ float fast_tanh(float x) {
    float a = fabsf(x);
    float e = __expf(-2.0f * a);          // underflows to 0 for large a -> r=1
    float r = (1.0f - e) / (1.0f + e);
    return copysignf(r, x);
}

__global__ void __launch_bounds__(NTH, 1) lstm_persist(
    const float* __restrict__ x,
    const float* __restrict__ W_ih,
    const float* __restrict__ W_hh,
    const float* __restrict__ b_ih,
    const float* __restrict__ b_hh,
    const float* __restrict__ W1,
    const float* __restrict__ b1,
    const float* __restrict__ Wout,
    u64* __restrict__ hbuf,             // 2 x 256 packets (MALL rail)
    float* __restrict__ out)
{
    const int w   = blockIdx.x;         // 0..31
    const int tid = threadIdx.x;
    const int wv  = tid >> 6;           // 0..7
    const int l   = tid & 63;
    const int rw  = l >> 3;             // 0..7 = (gate g, elem b)
    const int j   = l & 7;              // K-chunk
    const int g   = rw >> 1;
    const int b   = rw & 1;
    const bool is_out = (w == 0 && wv == 1);   // WG0 wave1 computes out[]

    __shared__ __align__(16) float h_lds[2][HID];   // parity double buffer
    __shared__ u64 gather_lds[8];                   // per-wave packet staging

    // each wave owns elements {16w + 2wv, 16w + 2wv + 1}; 8 rows (4 gates x 2)
    const int grow = g * HID + w * HSL + 2 * wv + b;

    // ---- weights, j-rotated order to match the LDS read schedule ----
    float wr[KW], wi[KX];
#pragma unroll
    for (int kk = 0; kk < 16; ++kk) {
        const int p = (kk + 2 * j) & 15;
        const float4 v4 = *(const float4*)&W_hh[grow * HID + j * KW + 4 * p];
        wr[4 * kk + 0] = v4.x; wr[4 * kk + 1] = v4.y;
        wr[4 * kk + 2] = v4.z; wr[4 * kk + 3] = v4.w;
    }
#pragma unroll
    for (int k = 0; k < KX; k += 4) {
        const float4 v4 = *(const float4*)&W_ih[grow * INP + j * KX + k];
        wi[k] = v4.x; wi[k + 1] = v4.y; wi[k + 2] = v4.z; wi[k + 3] = v4.w;
    }
    float brow = b_ih[grow] + b_hh[grow];

    // out-projection weights (WG0 wave1): lane l covers h indices l + 64*i
    float weff_o[8];
    float be = 0.0f;
#pragma unroll
    for (int i = 0; i < 8; ++i) weff_o[i] = 0.0f;
    if (is_out) {
#pragma unroll
        for (int i = 0; i < 8; ++i) {
            float s = 0.0f;
            for (int p = 0; p < 25; ++p) s += Wout[p] * W1[p * HID + l + 64 * i];
            weff_o[i] = s;
        }
        for (int p = 0; p < 25; ++p) be += b1[p] * Wout[p];
    }
    // pin against in-loop memory clobbers
#pragma unroll
    for (int k = 0; k < KW; ++k) asm volatile("" : "+v"(wr[k]));
#pragma unroll
    for (int k = 0; k < KX; ++k) asm volatile("" : "+v"(wi[k]));
#pragma unroll
    for (int i = 0; i < 8; ++i) asm volatile("" : "+v"(weff_o[i]));
    asm volatile("" : "+v"(brow));
    asm volatile("" : "+v"(be));

    float c = 0.0f;
    float xa[KX];
#pragma unroll
    for (int k = 0; k < KX; ++k) xa[k] = x[j * KX + k];

    bool dead = false;        // safety latch: never hang the device
    bool slowMode = false;    // sticky: pipelined rail declared dead
    int  slowSteps = 0;       // fallback-step count (t>=4 only)

#define TAGOK(p) (((((u32)(p)) ^ tLo) & 15u) == 0u && \
                  ((((u32)((p) >> 32)) ^ tHi) & 15u) == 0u)

    for (u32 t = 0; t <= T_SEQ; ++t) {
        if (t == T_SEQ && w != 0) break;   // only WG0 runs the tail iteration

        // ---- x-dot partials for step t (pure VALU; overlaps the poll) ----
        float xd0 = 0.0f, xd1 = 0.0f, xd2 = 0.0f, xd3 = 0.0f;
#pragma unroll
        for (int k = 0; k < KX; k += 4) {
            xd0 += wi[k + 0] * xa[k + 0];
            xd1 += wi[k + 1] * xa[k + 1];
            xd2 += wi[k + 2] * xa[k + 2];
            xd3 += wi[k + 3] * xa[k + 3];
        }
        // xa consumed -> prefetch x_{t+1}. Compute waves: before the barrier.
        // Poller: after the barrier (R12 placement).
        const int tn = (t + 1 < T_SEQ) ? (int)(t + 1) : (T_SEQ - 1);
        if (wv != 0) {
#pragma unroll
            for (int k = 0; k < KX; k += 4) {
                const float4 x4 = *(const float4*)&x[tn * INP + j * KX + k];
                xa[k + 0] = x4.x; xa[k + 1] = x4.y;
                xa[k + 2] = x4.z; xa[k + 3] = x4.w;
            }
        }

        // ---- wave0 fills h_lds: t=0 synthesizes h0=0; t>=1 pipelined poll
        //      (2 batches in flight, vmcnt(4) waits the older batch only),
        //      falling back to the R12-proven atomic loop on FT misses ----
        if (wv == 0 && !dead) {
            float2* HL = (float2*)h_lds[t & 1];
            if (t == 0) {
                float2 z; z.x = 0.0f; z.y = 0.0f;
                HL[l +   0] = z;
                HL[l +  64] = z;
                HL[l + 128] = z;
                HL[l + 192] = z;
            } else {
                const u64* P = hbuf + (t & 1) * NPK;
                const u64 a0 = (u64)(P + l);
                const u64 a1 = a0 +  64u * sizeof(u64);
                const u64 a2 = a0 + 128u * sizeof(u64);
                const u64 a3 = a0 + 192u * sizeof(u64);
                const u32 tLo = t & 15u;
                const u32 tHi = (t >> 4) & 15u;
                u64 r0 = 0, r1 = 0, r2 = 0, r3 = 0;
                bool got = false;

                if (!slowMode) {
                    u64 qa0, qa1, qa2, qa3, qb0, qb1, qb2, qb3;
                    // prime batch A then batch B (8 loads in flight; any
                    // stale leftovers from last step are OLDEST and drain
                    // for free inside the first vmcnt(4))
                    asm volatile(
                        "global_load_dwordx2 %0, %4, off sc0 sc1\n\t"
                        "global_load_dwordx2 %1, %5, off sc0 sc1\n\t"
                        "global_load_dwordx2 %2, %6, off sc0 sc1\n\t"
                        "global_load_dwordx2 %3, %7, off sc0 sc1"
                        : "=&v"(qa0), "=&v"(qa1), "=&v"(qa2), "=&v"(qa3)
                        : "v"(a0), "v"(a1), "v"(a2), "v"(a3) : "memory");
                    asm volatile(
                        "global_load_dwordx2 %0, %4, off sc0 sc1\n\t"
                        "global_load_dwordx2 %1, %5, off sc0 sc1\n\t"
                        "global_load_dwordx2 %2, %6, off sc0 sc1\n\t"
                        "global_load_dwordx2 %3, %7, off sc0 sc1"
                        : "=&v"(qb0), "=&v"(qb1), "=&v"(qb2), "=&v"(qb3)
                        : "v"(a0), "v"(a1), "v"(a2), "v"(a3) : "memory");
                    int it = 0;
                    while (true) {
                        // -- check batch A (older) --
                        asm volatile("s_waitcnt vmcnt(4)" ::: "memory");
                        __builtin_amdgcn_sched_barrier(0);
                        bool ok = TAGOK(qa0) && TAGOK(qa1) &&
                                  TAGOK(qa2) && TAGOK(qa3);
                        if (__ballot(ok) == ~0ull) {
                            r0 = qa0; r1 = qa1; r2 = qa2; r3 = qa3;
                            got = true; break;
                        }
                        asm volatile(
                            "global_load_dwordx2 %0, %4, off sc0 sc1\n\t"
                            "global_load_dwordx2 %1, %5, off sc0 sc1\n\t"
                            "global_load_dwordx2 %2, %6, off sc0 sc1\n\t"
                            "global_load_dwordx2 %3, %7, off sc0 sc1"
                            : "=&v"(qa0), "=&v"(qa1), "=&v"(qa2), "=&v"(qa3)
                            : "v"(a0), "v"(a1), "v"(a2), "v"(a3) : "memory");
                        if (++it > FT) break;
                        // -- check batch B (now older) --
                        asm volatile("s_waitcnt vmcnt(4)" ::: "memory");
                        __builtin_amdgcn_sched_barrier(0);
                        ok = TAGOK(qb0) && TAGOK(qb1) &&
                             TAGOK(qb2) && TAGOK(qb3);
                        if (__ballot(ok) == ~0ull) {
                            r0 = qb0; r1 = qb1; r2 = qb2; r3 = qb3;
                            got = true; break;
                        }
                        asm volatile(
                            "global_load_dwordx2 %0, %4, off sc0 sc1\n\t"
                            "global_load_dwordx2 %1, %5, off sc0 sc1\n\t"
                            "global_load_dwordx2 %2, %6, off sc0 sc1\n\t"
                            "global_load_dwordx2 %3, %7, off sc0 sc1"
                            : "=&v"(qb0), "=&v"(qb1), "=&v"(qb2), "=&v"(qb3)
                            : "v"(a0), "v"(a1), "v"(a2), "v"(a3) : "memory");
                        if (++it > FT) break;
                    }
                    if (!got && t >= 4) {
                        if (++slowSteps >= 8) slowMode = true;   // sticky
                    }
                }
                if (!got) {
                    // R12-proven fallback: agent atomic loads, full drain
                    asm volatile("s_waitcnt vmcnt(0)" ::: "memory");
                    __builtin_amdgcn_sched_barrier(0);
                    int guard = 0;
                    while (true) {
                        r0 = __hip_atomic_load(P + l, __ATOMIC_RELAXED,
                                               __HIP_MEMORY_SCOPE_AGENT);
                        r1 = __hip_atomic_load(P + l + 64, __ATOMIC_RELAXED,
                                               __HIP_MEMORY_SCOPE_AGENT);
                        r2 = __hip_atomic_load(P + l + 128, __ATOMIC_RELAXED,
                                               __HIP_MEMORY_SCOPE_AGENT);
                        r3 = __hip_atomic_load(P + l + 192, __ATOMIC_RELAXED,
                                               __HIP_MEMORY_SCOPE_AGENT);
                        const bool ok = TAGOK(r0) && TAGOK(r1) &&
                                        TAGOK(r2) && TAGOK(r3);
                        if (__ballot(ok) == ~0ull) break;
                        if (++guard > (1 << 22)) { dead = true; break; }
                    }
                }
                {
                    float2 h0, h1, h2, h3;
                    h0.x = __uint_as_float((u32)r0);
                    h0.y = __uint_as_float((u32)(r0 >> 32));
                    h1.x = __uint_as_float((u32)r1);
                    h1.y = __uint_as_float((u32)(r1 >> 32));
                    h2.x = __uint_as_float((u32)r2);
                    h2.y = __uint_as_float((u32)(r2 >> 32));
                    h3.x = __uint_as_float((u32)r3);
                    h3.y = __uint_as_float((u32)(r3 >> 32));
                    HL[l +   0] = h0;
                    HL[l +  64] = h1;
                    HL[l + 128] = h2;
                    HL[l + 192] = h3;
                }
            }
        }
        __syncthreads();   // barrier A (R12-exact)

        if (t < T_SEQ) {
            float a0 = xd0, a1 = xd1, a2 = xd2, a3 = xd3;
            const float4* hl4 = (const float4*)&h_lds[t & 1][j * KW];
#pragma unroll
            for (int kk = 0; kk < 16; ++kk) {
                const int p = (kk + 2 * j) & 15;
                const float4 h4 = hl4[p];
                a0 += wr[4 * kk + 0] * h4.x;
                a1 += wr[4 * kk + 1] * h4.y;
                a2 += wr[4 * kk + 2] * h4.z;
                a3 += wr[4 * kk + 3] * h4.w;
            }
            // poller's x-prefetch (after barrier, overlaps the h-dot; retires
            // ~a full step before its next poll touches vmcnt)
            if (wv == 0) {
#pragma unroll
                for (int k = 0; k < KX; k += 4) {
                    const float4 x4 = *(const float4*)&x[tn * INP + j * KX + k];
                    xa[k + 0] = x4.x; xa[k + 1] = x4.y;
                    xa[k + 2] = x4.z; xa[k + 3] = x4.w;
                }
            }
            // xor-butterfly over j: every lane holds its row's full sum
            float acc = (a0 + a1) + (a2 + a3);
            acc += __shfl_xor(acc, 1);
            acc += __shfl_xor(acc, 2);
            acc += __shfl_xor(acc, 4);
            acc += brow;
            // gates of element b live at rw = b, b+2, b+4, b+6 (valid l<16)
            const float ig = acc;
            const float fg = __shfl(acc, l + 16);
            const float gg = __shfl(acc, l + 32);
            const float og = __shfl(acc, l + 48);
            const float iv = fast_sigmoid(ig);
            const float fv = fast_sigmoid(fg);
            const float gv = fast_tanh(gg);
            const float ov = fast_sigmoid(og);
            c = fv * c + iv * gv;
            const float hv = ov * fast_tanh(c);
            // stage this wave's packet: 8-bit tag in-band — (t+1)&15 in
            // h_even low nibble, ((t+1)>>4)&15 in h_odd low nibble
            const float hv1 = __shfl(hv, 8);     // element b=1 (lane 8)
            if (l == 0) {
                const u32 b0  = (__float_as_uint(hv)  & ~15u) | ((t + 1) & 15u);
                const u32 b1v = (__float_as_uint(hv1) & ~15u) | (((t + 1) >> 4) & 15u);
                gather_lds[wv] = ((u64)b1v << 32) | (u64)b0;
            }
            __syncthreads();   // barrier B: all 8 packets staged (R12-exact)
            // ---- coalesced publish by a ROTATING compute wave (2 + t%6,
            //      never wave0/wave1): keeps publish stores out of wave0's
            //      vmcnt counts so the pipelined poll's counted waits are
            //      exact. Placement (post-barrier-B, pre-next-poll) verified
            //      deadlock-free in R16-R19. ----
            const int mwv = 2 + (int)(t % 6u);
            if (wv == mwv && l < 8) {
                const u64 pkt = gather_lds[l];
                __hip_atomic_store(&hbuf[((t + 1) & 1) * NPK + w * 8 + l],
                                   pkt, __ATOMIC_RELAXED,
                                   __HIP_MEMORY_SCOPE_AGENT);
            }
        }

        // out[t-1] = dot(h_t, w_eff) + b_eff — WG0 wave1, after publish
        if (is_out && t >= 1) {
            float pd = 0.0f;
#pragma unroll
            for (int i = 0; i < 8; ++i)
                pd += h_lds[t & 1][l + 64 * i] * weff_o[i];
            pd += __shfl_xor(pd, 1);
            pd += __shfl_xor(pd, 2);
            pd += __shfl_xor(pd, 4);
            pd += __shfl_xor(pd, 8);
            pd += __shfl_xor(pd, 16);
            pd += __shfl_xor(pd, 32);
            if (l == 0) out[t - 1] = pd + be;
        }
    }
#undef TAGOK
}

extern "C" void kernel_launch(void* const* d_in, const int* in_sizes, int n_in,
                              void* d_out, int out_size, void* d_ws, size_t ws_size,
                              hipStream_t stream)
{
    const float* x    = (const float*)d_in[0];
    const float* W_ih = (const float*)d_in[1];
    const float* W_hh = (const float*)d_in[2];
    const float* b_ih = (const float*)d_in[3];
    const float* b_hh = (const float*)d_in[4];
    const float* W1   = (const float*)d_in[5];
    const float* b1   = (const float*)d_in[6];
    const float* Wout = (const float*)d_in[7];
    float* out = (float*)d_out;

    u64* hbuf = (u64*)d_ws;    // 2 x 256 packets = 4 KB

    // zero packets (belt-and-braces; t=0 never reads the wire and the 8-bit
    // tag rejects stale generations anyway)
    hipMemsetAsync(d_ws, 0, 2 * NPK * sizeof(u64), stream);
    lstm_persist<<<NWG, NTH, 0, stream>>>(x, W_ih, W_hh, b_ih, b_hh, W1, b1,
                                          Wout, hbuf, out);
}